// Round 16
// baseline (129.756 us; speedup 1.0000x reference)
//
#include <hip/hip_runtime.h>
#include <hip/hip_fp16.h>

#define N_NODES 25000
#define N_EDGES 250000
#define ED 6
#define H1 64
#define H2 128
#define NBLK 977                   // ceil(250000/256)
#define NCHUNK 33
#define CHUNK_USH 4096             // per chunk: [ks16=8][lane=64][8 ush] = 8KB
#define W3S_USHORTS (NCHUNK*CHUNK_USH)
#define W2S_USHORTS (H2*H1)
#define SCAN_BLOCKS 98

typedef float f32x4 __attribute__((ext_vector_type(4)));
typedef float f32x16 __attribute__((ext_vector_type(16)));
typedef _Float16 f16x8 __attribute__((ext_vector_type(8)));
typedef __fp16 fp16x2 __attribute__((ext_vector_type(2)));
typedef unsigned int u32x4 __attribute__((ext_vector_type(4)));
typedef unsigned int u32x2 __attribute__((ext_vector_type(2)));

union F16x8U { u32x4 u; f16x8 h; };
union PKU    { fp16x2 p; unsigned u; };

__device__ __forceinline__ unsigned pkrtz(float lo, float hi) {
    PKU r; r.p = __builtin_amdgcn_cvt_pkrtz(lo, hi); return r.u;
}
__device__ __forceinline__ unsigned pk_mul_blo(unsigned h, unsigned x) {
    unsigned d;
    asm("v_pk_mul_f16 %0, %1, %2 op_sel:[0,0] op_sel_hi:[0,1]" : "=v"(d) : "v"(h), "v"(x));
    return d;
}
__device__ __forceinline__ unsigned pk_mul_bhi(unsigned h, unsigned x) {
    unsigned d;
    asm("v_pk_mul_f16 %0, %1, %2 op_sel:[1,0] op_sel_hi:[1,1]" : "=v"(d) : "v"(h), "v"(x));
    return d;
}
__device__ __forceinline__ f32x4 mfma16(f16x8 a, f16x8 b, f32x4 c) {
    return __builtin_amdgcn_mfma_f32_16x16x32_f16(a, b, c, 0, 0, 0);
}
__device__ __forceinline__ f32x16 mfma32(f16x8 a, f16x8 b, f32x16 c) {
    return __builtin_amdgcn_mfma_f32_32x32x16_f16(a, b, c, 0, 0, 0);
}
__device__ __forceinline__ void gload16(const void* g, void* l) {
    __builtin_amdgcn_global_load_lds(
        (const __attribute__((address_space(1))) unsigned int*)g,
        (__attribute__((address_space(3))) unsigned int*)l, 16, 0, 0);
}

// ---------------- init: zero cnt+agg + repack W3(+b3)/W2 -> fp16 -----------
// (w3s layout identical to rounds 13-15)
__global__ __launch_bounds__(256) void ecc_init(
    const float* __restrict__ W3, const float* __restrict__ b3,
    const float* __restrict__ W2,
    unsigned* __restrict__ cnt, unsigned short* __restrict__ w3s,
    unsigned short* __restrict__ w2s, float* __restrict__ agg)
{
    int idx = blockIdx.x * 256 + threadIdx.x;
    if (idx < W3S_USHORTS) {
        int c = idx >> 12, r = idx & 4095;
        int ks = r >> 9;
        int lane = (r >> 3) & 63;
        int j = r & 7;
        int o = lane & 31;
        int kp = c * 128 + ks * 16 + ((lane >> 5) << 3) + j;
        float v = 0.f;
        if (kp < 4096)      { int k = kp >> 5, i = kp & 31; v = W3[(o * 32 + i) * 128 + k]; }
        else if (kp < 4128) { v = b3[o * 32 + (kp - 4096)]; }
        __half hv = __float2half_rn(v);
        w3s[idx] = *reinterpret_cast<unsigned short*>(&hv);
    }
    if (idx < W2S_USHORTS) {
        __half hv = __float2half_rn(W2[idx]);
        w2s[idx] = *reinterpret_cast<unsigned short*>(&hv);
    }
    if (idx < N_NODES) cnt[idx] = 0u;
    if (idx < N_NODES * 32) agg[idx] = 0.f;
}

// ---------------- sort machinery -------------------------------------------
__global__ __launch_bounds__(256) void ecc_hist(
    const int* __restrict__ dst, unsigned* __restrict__ cnt,
    unsigned* __restrict__ rank)
{
    int e = blockIdx.x * 256 + threadIdx.x;
    if (e < N_EDGES) rank[e] = atomicAdd(&cnt[dst[e]], 1u);
}

__global__ __launch_bounds__(256) void ecc_scan1(
    const unsigned* __restrict__ cnt, unsigned* __restrict__ off,
    unsigned* __restrict__ bsum)
{
    __shared__ unsigned s[256];
    const int t = threadIdx.x, i = blockIdx.x * 256 + t;
    unsigned v = (i < N_NODES) ? cnt[i] : 0u;
    s[t] = v; __syncthreads();
    #pragma unroll
    for (int d = 1; d < 256; d <<= 1) {
        unsigned add = (t >= d) ? s[t - d] : 0u;
        __syncthreads(); s[t] += add; __syncthreads();
    }
    if (i < N_NODES) off[i] = s[t] - v;
    if (t == 255) bsum[blockIdx.x] = s[255];
}

__global__ __launch_bounds__(128) void ecc_scan2(
    const unsigned* __restrict__ bsum, unsigned* __restrict__ bsumx)
{
    __shared__ unsigned s[128];
    const int t = threadIdx.x;
    unsigned v = (t < SCAN_BLOCKS) ? bsum[t] : 0u;
    s[t] = v; __syncthreads();
    #pragma unroll
    for (int d = 1; d < 128; d <<= 1) {
        unsigned add = (t >= d) ? s[t - d] : 0u;
        __syncthreads(); s[t] += add; __syncthreads();
    }
    if (t < SCAN_BLOCKS) bsumx[t] = s[t] - v;
}

__global__ __launch_bounds__(256) void ecc_scan3(
    unsigned* __restrict__ off, const unsigned* __restrict__ bsumx)
{
    int i = blockIdx.x * 256 + threadIdx.x;
    if (i < N_NODES) off[i] += bsumx[blockIdx.x];
    if (i == 0) off[N_NODES] = N_EDGES;
}

// perm + per-block first-node index
__global__ __launch_bounds__(256) void ecc_perm(
    const int* __restrict__ dst, const unsigned* __restrict__ off,
    const unsigned* __restrict__ rank, unsigned* __restrict__ perm,
    int* __restrict__ bfirst)
{
    int e = blockIdx.x * 256 + threadIdx.x;
    if (e < N_EDGES) perm[off[dst[e]] + rank[e]] = (unsigned)e;
    if (e < NBLK) {
        const unsigned tile = (unsigned)e * 256u;
        int loN = 0, hiN = N_NODES;
        while (loN < hiN) {
            int mid = (loN + hiN) >> 1;
            if (off[mid + 1] > tile) hiN = mid; else loN = mid + 1;
        }
        bfirst[e] = loN;
    }
}

// ---------------- fused: MLP + K-split 32x32 GEMM + segmented scatter ------
// K-split wave specialization: wave w = (epair = w>>1) x (kshalf = w&1).
// Each wave computes a K-PARTIAL for 128 edges (mt=4) over its 4 of 8 ks16
// steps -> reads only half the B-chunk (halves LDS BW, the measured bound).
// Partials summed through fp32 LDS in the epilogue.
__global__ __launch_bounds__(256) void ecc_fused(
    const float* __restrict__ x,   const float* __restrict__ ea,
    const float* __restrict__ W1,  const float* __restrict__ b1,
    const unsigned short* __restrict__ w2s, const float* __restrict__ b2,
    const unsigned short* __restrict__ w3s,
    const int* __restrict__ src,   const unsigned* __restrict__ perm,
    const unsigned* __restrict__ off, const int* __restrict__ bfirst,
    float* __restrict__ agg)
{
    __shared__ __align__(16) unsigned short sm[256 * H2];       // 64KB h1s/h2s/partials
    __shared__ __align__(16) unsigned short wbuf[2][CHUNK_USH]; // 2 x 8KB B-chunks
    // LDS total = 81920 B exactly -> 2 blocks/CU. Do NOT add any more.

    const int t = threadIdx.x;
    const int tile = blockIdx.x * 256;
    const int slot = tile + t;
    const bool ev = (slot < N_EDGES);
    const unsigned je = ev ? perm[slot] : 0u;

    const int w = t >> 6, l = t & 63, lr = l & 15, kg = l >> 4;
    const int l31 = l & 31, l5 = l >> 5;
    const int epair  = w >> 1;      // edge half: rows epair*128 .. +127
    const int kshalf = w & 1;       // ks16 half: steps kshalf*4 .. +3

    // stage chunk 0 now — DMA overlaps the whole MLP phase
    gload16(w3s + t * 8,        &wbuf[0][t * 8]);
    gload16(w3s + 2048 + t * 8, &wbuf[0][2048 + t * 8]);

    // ---------------- phase 0a: L1 on VALU -> h1s (fp16, swizzled) ----------
    {
        float a[ED];
        #pragma unroll
        for (int c = 0; c < ED; ++c) a[c] = ev ? ea[(long)je * ED + c] : 0.f;

        float h1[H1];
        #pragma unroll
        for (int o = 0; o < H1; ++o) {
            float acc = b1[o];
            #pragma unroll
            for (int c = 0; c < ED; ++c) acc = fmaf(W1[o * ED + c], a[c], acc);
            h1[o] = fmaxf(acc, 0.f);
        }
        #pragma unroll
        for (int q = 0; q < 8; ++q) {
            u32x4 pk;
            #pragma unroll
            for (int j = 0; j < 4; ++j)
                pk[j] = pkrtz(h1[q*8 + 2*j], h1[q*8 + 2*j + 1]);
            const int boff = (t * 128 + q * 16) ^ ((t & 7) << 4);
            *(u32x4*)((char*)sm + boff) = pk;
        }
    }

    // ---------------- per-lane xs gather (4 m-tiles of 32 rows) -------------
    unsigned xsh[4][8];
    #pragma unroll
    for (int mt = 0; mt < 4; ++mt) {
        const int er = tile + epair * 128 + mt * 32 + l31;
        if (er < N_EDGES) {
            const float* xb = x + (long)src[perm[er]] * 32;
            const float4* xp = (const float4*)(xb + l5 * 8);
            const float4* xq = (const float4*)(xb + 16 + l5 * 8);
            float4 v0 = xp[0], v1 = xp[1], v2 = xq[0], v3 = xq[1];
            xsh[mt][0] = pkrtz(v0.x, v0.y); xsh[mt][1] = pkrtz(v0.z, v0.w);
            xsh[mt][2] = pkrtz(v1.x, v1.y); xsh[mt][3] = pkrtz(v1.z, v1.w);
            xsh[mt][4] = pkrtz(v2.x, v2.y); xsh[mt][5] = pkrtz(v2.z, v2.w);
            xsh[mt][6] = pkrtz(v3.x, v3.y); xsh[mt][7] = pkrtz(v3.z, v3.w);
        } else {
            #pragma unroll
            for (int j = 0; j < 8; ++j) xsh[mt][j] = 0u;
        }
    }

    // ---------------- phase 0b: layer 2 via 16x16 MFMA (fp16) ---------------
    {
        F16x8U hb[4][2];
        #pragma unroll
        for (int ne = 0; ne < 4; ++ne) {
            const int er = w * 64 + ne * 16 + lr;
            #pragma unroll
            for (int ks = 0; ks < 2; ++ks) {
                const int boff = (er * 128 + ks * 64 + kg * 16) ^ ((er & 7) << 4);
                hb[ne][ks].u = *(const u32x4*)((const char*)sm + boff);
            }
        }
        __syncthreads();   // all h1 reads complete before h2 overwrites

        #pragma unroll
        for (int mo = 0; mo < 8; ++mo) {
            F16x8U a2[2];
            #pragma unroll
            for (int ks = 0; ks < 2; ++ks)
                a2[ks].u = *(const u32x4*)(w2s + (mo*16 + lr) * 64 + ks*32 + kg*8);
            const float4 bv = *(const float4*)(b2 + mo*16 + kg*4);
            #pragma unroll
            for (int ne = 0; ne < 4; ++ne) {
                f32x4 c = (f32x4){0.f, 0.f, 0.f, 0.f};
                c = mfma16(a2[0].h, hb[ne][0].h, c);
                c = mfma16(a2[1].h, hb[ne][1].h, c);
                const unsigned p0 = pkrtz(fmaxf(c[0]+bv.x, 0.f), fmaxf(c[1]+bv.y, 0.f));
                const unsigned p1 = pkrtz(fmaxf(c[2]+bv.z, 0.f), fmaxf(c[3]+bv.w, 0.f));
                const int er = w * 64 + ne * 16 + lr;
                const int boff = (er * 256 + (mo*16 + kg*4) * 2) ^ ((er & 7) << 4);
                *(u32x2*)((char*)sm + boff) = (u32x2){p0, p1};
            }
        }
    }

    f32x16 acc[4];
    #pragma unroll
    for (int mt = 0; mt < 4; ++mt)
        #pragma unroll
        for (int i = 0; i < 16; ++i) acc[mt][i] = 0.f;

    __syncthreads();   // h2s ready; chunk-0 DMA drained by this barrier

    // ---------------- K loop: 32 chunks (each wave: its ks-half only) -------
    int cur = 0;
    #pragma unroll 1
    for (int c = 0; c < 32; ++c) {
        {   // stage next chunk into the other buffer
            const unsigned short* gs = w3s + (c + 1) * CHUNK_USH + t * 8;
            gload16(gs,        &wbuf[cur ^ 1][t * 8]);
            gload16(gs + 2048, &wbuf[cur ^ 1][2048 + t * 8]);
        }
        const char* wb = (const char*)wbuf[cur] + kshalf * 4096 + l * 16;

        // h2 pair (k = c*4 + kshalf*2, +1) per m-tile: one b32 each
        unsigned hv[4];
        #pragma unroll
        for (int mt = 0; mt < 4; ++mt) {
            const int row = epair * 128 + mt * 32 + l31;
            const int boff = (row * 256 + c * 8 + kshalf * 4) ^ ((row & 7) << 4);
            hv[mt] = *(const unsigned*)((const char*)sm + boff);
        }

        __builtin_amdgcn_s_setprio(1);
        #pragma unroll
        for (int ks = 0; ks < 4; ++ks) {       // local ks16 within our half
            F16x8U bf;
            bf.u = *(const u32x4*)(wb + ks * 1024);
            const int xb = (ks & 1) * 4;       // i-window select
            #pragma unroll
            for (int mt = 0; mt < 4; ++mt) {
                F16x8U af;
                if (ks & 2) {                  // second k of the pair -> hi half
                    af.u[0] = pk_mul_bhi(hv[mt], xsh[mt][xb + 0]);
                    af.u[1] = pk_mul_bhi(hv[mt], xsh[mt][xb + 1]);
                    af.u[2] = pk_mul_bhi(hv[mt], xsh[mt][xb + 2]);
                    af.u[3] = pk_mul_bhi(hv[mt], xsh[mt][xb + 3]);
                } else {
                    af.u[0] = pk_mul_blo(hv[mt], xsh[mt][xb + 0]);
                    af.u[1] = pk_mul_blo(hv[mt], xsh[mt][xb + 1]);
                    af.u[2] = pk_mul_blo(hv[mt], xsh[mt][xb + 2]);
                    af.u[3] = pk_mul_blo(hv[mt], xsh[mt][xb + 3]);
                }
                acc[mt] = mfma32(af.h, bf.h, acc[mt]);
            }
        }
        __builtin_amdgcn_s_setprio(0);

        __syncthreads();   // drains DMA + all waves done with wb
        cur ^= 1;
    }
    if (kshalf == 0) {   // b3 tail (chunk 32, ks16 0..1 only): A = fp16(xs)
        const char* wb = (const char*)wbuf[cur] + l * 16;
        F16x8U bf0, bf1;
        bf0.u = *(const u32x4*)(wb);
        bf1.u = *(const u32x4*)(wb + 1024);
        #pragma unroll
        for (int mt = 0; mt < 4; ++mt) {
            F16x8U af;
            af.u = (u32x4){xsh[mt][0], xsh[mt][1], xsh[mt][2], xsh[mt][3]};
            acc[mt] = mfma32(af.h, bf0.h, acc[mt]);
            af.u = (u32x4){xsh[mt][4], xsh[mt][5], xsh[mt][6], xsh[mt][7]};
            acc[mt] = mfma32(af.h, bf1.h, acc[mt]);
        }
    }

    // ---------------- epilogue A: fp32 K-partials -> LDS [kshalf][el][o] ----
    // C layout (m74/m101): col=o=l31, row = (reg&3) + 8*(reg>>2) + 4*l5.
    __syncthreads();   // everyone done reading sm (h2s region)
    {
        float* pm = (float*)sm;   // [2][256][32] fp32 = 64KB
        #pragma unroll
        for (int mt = 0; mt < 4; ++mt) {
            #pragma unroll
            for (int rg = 0; rg < 16; ++rg) {
                const int el = epair * 128 + mt * 32 + (rg & 3) + 8 * (rg >> 2) + 4 * l5;
                pm[kshalf * 8192 + el * 32 + l31] = acc[mt][rg];
            }
        }
    }
    __syncthreads();

    // ---------------- epilogue B: segmented mean-sum -> atomicAdd(agg) ------
    {
        const float* pm = (const float*)sm;
        const int n0 = bfirst[blockIdx.x];
        const int tend = tile + 256;
        #pragma unroll 1
        for (int p = t; ; p += 256) {
            const int n = n0 + (p >> 5);
            if (n >= N_NODES) break;
            const unsigned lo = off[n], hi = off[n + 1];
            if ((int)lo >= tend) break;
            const int o = p & 31;
            const int jb = max((int)lo, tile), jend = min((int)hi, tend);
            if (jend > jb) {
                float s = 0.f;
                for (int j = jb; j < jend; ++j) {
                    const int jl = j - tile;
                    s += pm[jl * 32 + o] + pm[8192 + jl * 32 + o];
                }
                atomicAdd(&agg[(long)n * 32 + o], s);
            }
        }
    }
}

// ---------------- finalize: relu(agg / max(deg,1)) -------------------------
__global__ __launch_bounds__(256) void ecc_finalize(
    const float* __restrict__ agg, const unsigned* __restrict__ cnt,
    float* __restrict__ out)
{
    const int i = blockIdx.x * 256 + threadIdx.x;
    if (i >= N_NODES * 32) return;
    const int n = i >> 5;
    const float d = fmaxf((float)cnt[n], 1.f);
    out[i] = fmaxf(agg[i] / d, 0.f);
}

extern "C" void kernel_launch(void* const* d_in, const int* in_sizes, int n_in,
                              void* d_out, int out_size, void* d_ws, size_t ws_size,
                              hipStream_t stream) {
    const float* x   = (const float*)d_in[0];
    const float* ea  = (const float*)d_in[1];
    const float* W1  = (const float*)d_in[2];
    const float* b1  = (const float*)d_in[3];
    const float* W2  = (const float*)d_in[4];
    const float* b2  = (const float*)d_in[5];
    const float* W3  = (const float*)d_in[6];
    const float* b3  = (const float*)d_in[7];
    const int*   src = (const int*)d_in[8];
    const int*   dst = (const int*)d_in[9];
    float* out = (float*)d_out;

    char* p = (char*)d_ws;
    unsigned short* w3s = (unsigned short*)p; p += W3S_USHORTS * 2;  // 270336
    unsigned short* w2s = (unsigned short*)p; p += 16384;
    unsigned* cnt   = (unsigned*)p; p += 100096;
    unsigned* off   = (unsigned*)p; p += 100352;
    unsigned* bsum  = (unsigned*)p; p += 512;
    unsigned* bsumx = (unsigned*)p; p += 512;
    int*      bfirst= (int*)p;      p += 4096;
    unsigned* rank  = (unsigned*)p; p += 1000192;
    unsigned* perm  = (unsigned*)p; p += 1000192;
    float*    agg   = (float*)p;                                     // 3.2MB

    ecc_init<<<(N_NODES * 32 + 255) / 256, 256, 0, stream>>>(W3, b3, W2, cnt, w3s, w2s, agg);
    ecc_hist<<<NBLK, 256, 0, stream>>>(dst, cnt, rank);
    ecc_scan1<<<SCAN_BLOCKS, 256, 0, stream>>>(cnt, off, bsum);
    ecc_scan2<<<1, 128, 0, stream>>>(bsum, bsumx);
    ecc_scan3<<<SCAN_BLOCKS, 256, 0, stream>>>(off, bsumx);
    ecc_perm<<<NBLK, 256, 0, stream>>>(dst, off, rank, perm, bfirst);
    ecc_fused<<<NBLK, 256, 0, stream>>>(x, ea, W1, b1, w2s, b2, w3s, src, perm, off, bfirst, agg);
    ecc_finalize<<<(N_NODES * 32 + 255) / 256, 256, 0, stream>>>(agg, cnt, out);
}

// Round 17
// 124.994 us; speedup vs baseline: 1.0381x; 1.0381x over previous
//
#include <hip/hip_runtime.h>
#include <hip/hip_fp16.h>

#define N_NODES 25000
#define N_EDGES 250000
#define ED 6
#define H1 64
#define H2 128
#define NBLK 977                   // ceil(250000/256)
#define NCHUNK 33
#define CHUNK_USH 4096             // per chunk: [ks16=8][lane=64][8 ush] = 8KB
#define W3S_USHORTS (NCHUNK*CHUNK_USH)
#define W2S_USHORTS (H2*H1)
#define SCAN_BLOCKS 98

typedef float f32x4 __attribute__((ext_vector_type(4)));
typedef float f32x16 __attribute__((ext_vector_type(16)));
typedef _Float16 f16x8 __attribute__((ext_vector_type(8)));
typedef __fp16 fp16x2 __attribute__((ext_vector_type(2)));
typedef unsigned int u32x4 __attribute__((ext_vector_type(4)));
typedef unsigned int u32x2 __attribute__((ext_vector_type(2)));

union F16x8U { u32x4 u; f16x8 h; };
union PKU    { fp16x2 p; unsigned u; };

__device__ __forceinline__ unsigned pkrtz(float lo, float hi) {
    PKU r; r.p = __builtin_amdgcn_cvt_pkrtz(lo, hi); return r.u;
}
__device__ __forceinline__ unsigned pk_mul_blo(unsigned h, unsigned x) {
    unsigned d;
    asm("v_pk_mul_f16 %0, %1, %2 op_sel:[0,0] op_sel_hi:[0,1]" : "=v"(d) : "v"(h), "v"(x));
    return d;
}
__device__ __forceinline__ unsigned pk_mul_bhi(unsigned h, unsigned x) {
    unsigned d;
    asm("v_pk_mul_f16 %0, %1, %2 op_sel:[1,0] op_sel_hi:[1,1]" : "=v"(d) : "v"(h), "v"(x));
    return d;
}
__device__ __forceinline__ f32x4 mfma16(f16x8 a, f16x8 b, f32x4 c) {
    return __builtin_amdgcn_mfma_f32_16x16x32_f16(a, b, c, 0, 0, 0);
}
__device__ __forceinline__ f32x16 mfma32(f16x8 a, f16x8 b, f32x16 c) {
    return __builtin_amdgcn_mfma_f32_32x32x16_f16(a, b, c, 0, 0, 0);
}
__device__ __forceinline__ void gload16(const void* g, void* l) {
    __builtin_amdgcn_global_load_lds(
        (const __attribute__((address_space(1))) unsigned int*)g,
        (__attribute__((address_space(3))) unsigned int*)l, 16, 0, 0);
}

// ---------------- init: zero cnt+agg + repack W3(+b3)/W2 -> fp16 -----------
// (w3s layout identical to rounds 13-15)
__global__ __launch_bounds__(256) void ecc_init(
    const float* __restrict__ W3, const float* __restrict__ b3,
    const float* __restrict__ W2,
    unsigned* __restrict__ cnt, unsigned short* __restrict__ w3s,
    unsigned short* __restrict__ w2s, float* __restrict__ agg)
{
    int idx = blockIdx.x * 256 + threadIdx.x;
    if (idx < W3S_USHORTS) {
        int c = idx >> 12, r = idx & 4095;
        int ks = r >> 9;
        int lane = (r >> 3) & 63;
        int j = r & 7;
        int o = lane & 31;
        int kp = c * 128 + ks * 16 + ((lane >> 5) << 3) + j;
        float v = 0.f;
        if (kp < 4096)      { int k = kp >> 5, i = kp & 31; v = W3[(o * 32 + i) * 128 + k]; }
        else if (kp < 4128) { v = b3[o * 32 + (kp - 4096)]; }
        __half hv = __float2half_rn(v);
        w3s[idx] = *reinterpret_cast<unsigned short*>(&hv);
    }
    if (idx < W2S_USHORTS) {
        __half hv = __float2half_rn(W2[idx]);
        w2s[idx] = *reinterpret_cast<unsigned short*>(&hv);
    }
    if (idx < N_NODES) cnt[idx] = 0u;
    if (idx < N_NODES * 32) agg[idx] = 0.f;
}

// ---------------- sort machinery -------------------------------------------
__global__ __launch_bounds__(256) void ecc_hist(
    const int* __restrict__ dst, unsigned* __restrict__ cnt,
    unsigned* __restrict__ rank)
{
    int e = blockIdx.x * 256 + threadIdx.x;
    if (e < N_EDGES) rank[e] = atomicAdd(&cnt[dst[e]], 1u);
}

__global__ __launch_bounds__(256) void ecc_scan1(
    const unsigned* __restrict__ cnt, unsigned* __restrict__ off,
    unsigned* __restrict__ bsum)
{
    __shared__ unsigned s[256];
    const int t = threadIdx.x, i = blockIdx.x * 256 + t;
    unsigned v = (i < N_NODES) ? cnt[i] : 0u;
    s[t] = v; __syncthreads();
    #pragma unroll
    for (int d = 1; d < 256; d <<= 1) {
        unsigned add = (t >= d) ? s[t - d] : 0u;
        __syncthreads(); s[t] += add; __syncthreads();
    }
    if (i < N_NODES) off[i] = s[t] - v;
    if (t == 255) bsum[blockIdx.x] = s[255];
}

// scan2+scan3 merged: each block wave-reduces its own base from bsum
// (<= SCAN_BLOCKS = 98 <= 128 values; lanes t and t+64 cover them).
__global__ __launch_bounds__(256) void ecc_scan23(
    unsigned* __restrict__ off, const unsigned* __restrict__ bsum)
{
    __shared__ unsigned sbase;
    const int t = threadIdx.x, b = blockIdx.x;
    if (t < 64) {
        unsigned v = 0u;
        if (t < b) v = bsum[t];
        if (t + 64 < b) v += bsum[t + 64];
        #pragma unroll
        for (int d = 32; d >= 1; d >>= 1) v += __shfl_down(v, d, 64);
        if (t == 0) sbase = v;
    }
    __syncthreads();
    const int i = b * 256 + t;
    if (i < N_NODES) off[i] += sbase;
    if (b == 0 && t == 0) off[N_NODES] = N_EDGES;
}

// perm + per-block first-node index
__global__ __launch_bounds__(256) void ecc_perm(
    const int* __restrict__ dst, const unsigned* __restrict__ off,
    const unsigned* __restrict__ rank, unsigned* __restrict__ perm,
    int* __restrict__ bfirst)
{
    int e = blockIdx.x * 256 + threadIdx.x;
    if (e < N_EDGES) perm[off[dst[e]] + rank[e]] = (unsigned)e;
    if (e < NBLK) {
        const unsigned tile = (unsigned)e * 256u;
        int loN = 0, hiN = N_NODES;
        while (loN < hiN) {
            int mid = (loN + hiN) >> 1;
            if (off[mid + 1] > tile) hiN = mid; else loN = mid + 1;
        }
        bfirst[e] = loN;
    }
}

// ---------------- fused: MLP + 32x32 GEMM + in-block segmented scatter -----
// Round-15 structure (best known: 94.1 us), with s_setprio removed
// (m190: setprio hurts lockstep barrier-synced GEMM loops).
__global__ __launch_bounds__(256) void ecc_fused(
    const float* __restrict__ x,   const float* __restrict__ ea,
    const float* __restrict__ W1,  const float* __restrict__ b1,
    const unsigned short* __restrict__ w2s, const float* __restrict__ b2,
    const unsigned short* __restrict__ w3s,
    const int* __restrict__ src,   const unsigned* __restrict__ perm,
    const unsigned* __restrict__ off, const int* __restrict__ bfirst,
    float* __restrict__ agg)
{
    __shared__ __align__(16) unsigned short sm[256 * H2];       // 64KB h1s/h2s/msgT
    __shared__ __align__(16) unsigned short wbuf[2][CHUNK_USH]; // 2 x 8KB B-chunks
    // LDS total = 81920 B exactly -> 2 blocks/CU. Do NOT add any more.

    const int t = threadIdx.x;
    const int tile = blockIdx.x * 256;
    const int slot = tile + t;
    const bool ev = (slot < N_EDGES);
    const unsigned je = ev ? perm[slot] : 0u;

    const int w = t >> 6, l = t & 63, lr = l & 15, kg = l >> 4;
    const int l31 = l & 31, l5 = l >> 5;

    // stage chunk 0 now — DMA overlaps the whole MLP phase
    gload16(w3s + t * 8,        &wbuf[0][t * 8]);
    gload16(w3s + 2048 + t * 8, &wbuf[0][2048 + t * 8]);

    // ---------------- phase 0a: L1 on VALU -> h1s (fp16, swizzled) ----------
    {
        float a[ED];
        #pragma unroll
        for (int c = 0; c < ED; ++c) a[c] = ev ? ea[(long)je * ED + c] : 0.f;

        float h1[H1];
        #pragma unroll
        for (int o = 0; o < H1; ++o) {
            float acc = b1[o];
            #pragma unroll
            for (int c = 0; c < ED; ++c) acc = fmaf(W1[o * ED + c], a[c], acc);
            h1[o] = fmaxf(acc, 0.f);
        }
        #pragma unroll
        for (int q = 0; q < 8; ++q) {
            u32x4 pk;
            #pragma unroll
            for (int j = 0; j < 4; ++j)
                pk[j] = pkrtz(h1[q*8 + 2*j], h1[q*8 + 2*j + 1]);
            const int boff = (t * 128 + q * 16) ^ ((t & 7) << 4);
            *(u32x4*)((char*)sm + boff) = pk;
        }
    }

    // ---------------- per-lane xs gather (32x32 layout) ---------------------
    unsigned xsh[2][8];
    #pragma unroll
    for (int mt = 0; mt < 2; ++mt) {
        const int er = tile + w * 64 + mt * 32 + l31;
        if (er < N_EDGES) {
            const float* xb = x + (long)src[perm[er]] * 32;
            const float4* xp = (const float4*)(xb + l5 * 8);
            const float4* xq = (const float4*)(xb + 16 + l5 * 8);
            float4 v0 = xp[0], v1 = xp[1], v2 = xq[0], v3 = xq[1];
            xsh[mt][0] = pkrtz(v0.x, v0.y); xsh[mt][1] = pkrtz(v0.z, v0.w);
            xsh[mt][2] = pkrtz(v1.x, v1.y); xsh[mt][3] = pkrtz(v1.z, v1.w);
            xsh[mt][4] = pkrtz(v2.x, v2.y); xsh[mt][5] = pkrtz(v2.z, v2.w);
            xsh[mt][6] = pkrtz(v3.x, v3.y); xsh[mt][7] = pkrtz(v3.z, v3.w);
        } else {
            #pragma unroll
            for (int j = 0; j < 8; ++j) xsh[mt][j] = 0u;
        }
    }

    // ---------------- phase 0b: layer 2 via 16x16 MFMA (fp16) ---------------
    {
        F16x8U hb[4][2];
        #pragma unroll
        for (int ne = 0; ne < 4; ++ne) {
            const int er = w * 64 + ne * 16 + lr;
            #pragma unroll
            for (int ks = 0; ks < 2; ++ks) {
                const int boff = (er * 128 + ks * 64 + kg * 16) ^ ((er & 7) << 4);
                hb[ne][ks].u = *(const u32x4*)((const char*)sm + boff);
            }
        }
        __syncthreads();   // all h1 reads complete before h2 overwrites

        #pragma unroll
        for (int mo = 0; mo < 8; ++mo) {
            F16x8U a2[2];
            #pragma unroll
            for (int ks = 0; ks < 2; ++ks)
                a2[ks].u = *(const u32x4*)(w2s + (mo*16 + lr) * 64 + ks*32 + kg*8);
            const float4 bv = *(const float4*)(b2 + mo*16 + kg*4);
            #pragma unroll
            for (int ne = 0; ne < 4; ++ne) {
                f32x4 c = (f32x4){0.f, 0.f, 0.f, 0.f};
                c = mfma16(a2[0].h, hb[ne][0].h, c);
                c = mfma16(a2[1].h, hb[ne][1].h, c);
                const unsigned p0 = pkrtz(fmaxf(c[0]+bv.x, 0.f), fmaxf(c[1]+bv.y, 0.f));
                const unsigned p1 = pkrtz(fmaxf(c[2]+bv.z, 0.f), fmaxf(c[3]+bv.w, 0.f));
                const int er = w * 64 + ne * 16 + lr;
                const int boff = (er * 256 + (mo*16 + kg*4) * 2) ^ ((er & 7) << 4);
                *(u32x2*)((char*)sm + boff) = (u32x2){p0, p1};
            }
        }
    }

    f32x16 acc[2];
    #pragma unroll
    for (int i = 0; i < 16; ++i) { acc[0][i] = 0.f; acc[1][i] = 0.f; }

    __syncthreads();   // h2s ready; chunk-0 DMA drained by this barrier

    // ---------------- K loop: 32 chunks + b3 tail, 32x32x16 MFMA ------------
    int cur = 0;
    #pragma unroll 1
    for (int c = 0; c < 32; ++c) {
        {   // stage next chunk into the other buffer
            const unsigned short* gs = w3s + (c + 1) * CHUNK_USH + t * 8;
            gload16(gs,        &wbuf[cur ^ 1][t * 8]);
            gload16(gs + 2048, &wbuf[cur ^ 1][2048 + t * 8]);
        }
        const char* wb = (const char*)wbuf[cur] + l * 16;

        u32x2 hv[2];
        #pragma unroll
        for (int mt = 0; mt < 2; ++mt) {
            const int row = w * 64 + mt * 32 + l31;
            const int boff = (row * 256 + c * 8) ^ ((row & 7) << 4);
            hv[mt] = *(const u32x2*)((const char*)sm + boff);
        }

        #pragma unroll
        for (int ks = 0; ks < 8; ++ks) {
            F16x8U bf;
            bf.u = *(const u32x4*)(wb + ks * 1024);
            const int kl = ks >> 1;
            const int xb = (ks & 1) * 4;
            #pragma unroll
            for (int mt = 0; mt < 2; ++mt) {
                const unsigned h01 = hv[mt][kl >> 1];
                F16x8U af;
                if (kl & 1) {
                    af.u[0] = pk_mul_bhi(h01, xsh[mt][xb + 0]);
                    af.u[1] = pk_mul_bhi(h01, xsh[mt][xb + 1]);
                    af.u[2] = pk_mul_bhi(h01, xsh[mt][xb + 2]);
                    af.u[3] = pk_mul_bhi(h01, xsh[mt][xb + 3]);
                } else {
                    af.u[0] = pk_mul_blo(h01, xsh[mt][xb + 0]);
                    af.u[1] = pk_mul_blo(h01, xsh[mt][xb + 1]);
                    af.u[2] = pk_mul_blo(h01, xsh[mt][xb + 2]);
                    af.u[3] = pk_mul_blo(h01, xsh[mt][xb + 3]);
                }
                acc[mt] = mfma32(af.h, bf.h, acc[mt]);
            }
        }

        __syncthreads();
        cur ^= 1;
    }
    {   // b3 tail
        const char* wb = (const char*)wbuf[cur] + l * 16;
        F16x8U bf0, bf1;
        bf0.u = *(const u32x4*)(wb);
        bf1.u = *(const u32x4*)(wb + 1024);
        #pragma unroll
        for (int mt = 0; mt < 2; ++mt) {
            F16x8U af;
            af.u = (u32x4){xsh[mt][0], xsh[mt][1], xsh[mt][2], xsh[mt][3]};
            acc[mt] = mfma32(af.h, bf0.h, acc[mt]);
            af.u = (u32x4){xsh[mt][4], xsh[mt][5], xsh[mt][6], xsh[mt][7]};
            acc[mt] = mfma32(af.h, bf1.h, acc[mt]);
        }
    }

    // ---------------- epilogue A: transpose C through LDS -> [slot][o] fp16 --
    // C layout (m74/m101): col=o=l31, row = (reg&3) + 8*(reg>>2) + 4*l5.
    __syncthreads();   // everyone done reading sm (h2s region)
    {
        unsigned short* msgl = (unsigned short*)sm;   // [256][32] fp16, 16KB
        #pragma unroll
        for (int mt = 0; mt < 2; ++mt) {
            #pragma unroll
            for (int rg = 0; rg < 16; ++rg) {
                const int el = w * 64 + mt * 32 + (rg & 3) + 8 * (rg >> 2) + 4 * l5;
                PKU hv2; hv2.p = __builtin_amdgcn_cvt_pkrtz(acc[mt][rg], 0.f);
                msgl[el * 32 + l31] = (unsigned short)(hv2.u & 0xFFFFu);
            }
        }
    }
    __syncthreads();

    // ---------------- epilogue B: segmented mean-sum -> atomicAdd(agg) ------
    {
        const unsigned short* msgl = (const unsigned short*)sm;
        const int n0 = bfirst[blockIdx.x];
        const int tend = tile + 256;
        #pragma unroll 1
        for (int p = t; ; p += 256) {
            const int n = n0 + (p >> 5);
            if (n >= N_NODES) break;
            const unsigned lo = off[n], hi = off[n + 1];
            if ((int)lo >= tend) break;
            const int o = p & 31;
            const int jb = max((int)lo, tile), jend = min((int)hi, tend);
            if (jend > jb) {
                float s = 0.f;
                for (int j = jb; j < jend; ++j) {
                    union { unsigned short u; _Float16 h; } v;
                    v.u = msgl[(j - tile) * 32 + o];
                    s += (float)v.h;
                }
                atomicAdd(&agg[(long)n * 32 + o], s);
            }
        }
    }
}

// ---------------- finalize: relu(agg / max(deg,1)) -------------------------
__global__ __launch_bounds__(256) void ecc_finalize(
    const float* __restrict__ agg, const unsigned* __restrict__ cnt,
    float* __restrict__ out)
{
    const int i = blockIdx.x * 256 + threadIdx.x;
    if (i >= N_NODES * 32) return;
    const int n = i >> 5;
    const float d = fmaxf((float)cnt[n], 1.f);
    out[i] = fmaxf(agg[i] / d, 0.f);
}

extern "C" void kernel_launch(void* const* d_in, const int* in_sizes, int n_in,
                              void* d_out, int out_size, void* d_ws, size_t ws_size,
                              hipStream_t stream) {
    const float* x   = (const float*)d_in[0];
    const float* ea  = (const float*)d_in[1];
    const float* W1  = (const float*)d_in[2];
    const float* b1  = (const float*)d_in[3];
    const float* W2  = (const float*)d_in[4];
    const float* b2  = (const float*)d_in[5];
    const float* W3  = (const float*)d_in[6];
    const float* b3  = (const float*)d_in[7];
    const int*   src = (const int*)d_in[8];
    const int*   dst = (const int*)d_in[9];
    float* out = (float*)d_out;

    char* p = (char*)d_ws;
    unsigned short* w3s = (unsigned short*)p; p += W3S_USHORTS * 2;  // 270336
    unsigned short* w2s = (unsigned short*)p; p += 16384;
    unsigned* cnt   = (unsigned*)p; p += 100096;
    unsigned* off   = (unsigned*)p; p += 100352;
    unsigned* bsum  = (unsigned*)p; p += 512;
    int*      bfirst= (int*)p;      p += 4096;
    unsigned* rank  = (unsigned*)p; p += 1000192;
    unsigned* perm  = (unsigned*)p; p += 1000192;
    float*    agg   = (float*)p;                                     // 3.2MB

    ecc_init<<<(N_NODES * 32 + 255) / 256, 256, 0, stream>>>(W3, b3, W2, cnt, w3s, w2s, agg);
    ecc_hist<<<NBLK, 256, 0, stream>>>(dst, cnt, rank);
    ecc_scan1<<<SCAN_BLOCKS, 256, 0, stream>>>(cnt, off, bsum);
    ecc_scan23<<<SCAN_BLOCKS, 256, 0, stream>>>(off, bsum);
    ecc_perm<<<NBLK, 256, 0, stream>>>(dst, off, rank, perm, bfirst);
    ecc_fused<<<NBLK, 256, 0, stream>>>(x, ea, W1, b1, w2s, b2, w3s, src, perm, off, bfirst, agg);
    ecc_finalize<<<(N_NODES * 32 + 255) / 256, 256, 0, stream>>>(agg, cnt, out);
}